// Round 4
// baseline (221.700 us; speedup 1.0000x reference)
//
#include <hip/hip_runtime.h>

constexpr int Bc = 8, Hc = 16, Sc = 4096, Dc = 64;
constexpr int BH = Bc * Hc;               // 128
constexpr int SS = 8;                     // s-split chunks in k1
constexpr int CHUNK = Sc / SS;            // 512 rows per block
constexpr int ROWS_STAGE = 32;            // rows staged in LDS per step
constexpr int NSTAGE = CHUNK / ROWS_STAGE; // 16
constexpr int MM = Dc * Dc;               // 4096 floats of M per (bh)
constexpr int QT = 128;                   // q-rows per block in k3

// ---- Kernel 1: partial M = sum_s k outer v (f32 fast), partial z (f64 exact) ----
__global__ __launch_bounds__(256) void k1_accum(const float* __restrict__ K,
                                                const float* __restrict__ V,
                                                float* __restrict__ Pm,
                                                double* __restrict__ Pz) {
  const int blk = blockIdx.x;
  const int bh = blk >> 3;       // 0..127
  const int ck = blk & 7;        // 0..7
  const size_t base = ((size_t)bh * Sc + (size_t)ck * CHUNK) * Dc;
  const float4* gk4 = (const float4*)(K + base);
  const float4* gv4 = (const float4*)(V + base);

  __shared__ __align__(16) float lk[ROWS_STAGE][Dc];
  __shared__ __align__(16) float lv[ROWS_STAGE][Dc];

  const int tid = threadIdx.x;
  const int d0 = (tid >> 4) * 4;   // 0..60
  const int e0 = (tid & 15) * 4;   // 0..60
  float acc[4][4] = {};
  double zacc = 0.0;               // exact z partial (error ~1e-13, << f32 half-ulp)

  // prologue: stage 0
  float4 rk0 = gk4[tid], rk1 = gk4[tid + 256];
  float4 rv0 = gv4[tid], rv1 = gv4[tid + 256];
  {
    const int r0 = tid >> 4, c0 = (tid * 4) & 63;
    *(float4*)&lk[r0][c0] = rk0; *(float4*)&lk[r0 + 16][c0] = rk1;
    *(float4*)&lv[r0][c0] = rv0; *(float4*)&lv[r0 + 16][c0] = rv1;
  }
  __syncthreads();

  for (int st = 0; st < NSTAGE; ++st) {
    // prefetch next stage into registers (latency hidden under compute)
    if (st + 1 < NSTAGE) {
      const int b = (st + 1) * (ROWS_STAGE * Dc / 4);
      rk0 = gk4[b + tid]; rk1 = gk4[b + tid + 256];
      rv0 = gv4[b + tid]; rv1 = gv4[b + tid + 256];
    }
    #pragma unroll
    for (int s = 0; s < ROWS_STAGE; ++s) {
      const float4 k4 = *(const float4*)&lk[s][d0];
      const float4 v4 = *(const float4*)&lv[s][e0];
      const float* kk = (const float*)&k4;
      const float* vv = (const float*)&v4;
      #pragma unroll
      for (int i = 0; i < 4; ++i)
        #pragma unroll
        for (int j = 0; j < 4; ++j)
          acc[i][j] = fmaf(kk[i], vv[j], acc[i][j]);
    }
    // z accumulation: wave 0 only, f64, conflict-free consecutive-word reads
    if (tid < Dc) {
      #pragma unroll
      for (int s = 0; s < ROWS_STAGE; ++s) zacc += (double)lk[s][tid];
    }
    __syncthreads();               // everyone done reading lk/lv
    if (st + 1 < NSTAGE) {
      const int r0 = tid >> 4, c0 = (tid * 4) & 63;
      *(float4*)&lk[r0][c0] = rk0; *(float4*)&lk[r0 + 16][c0] = rk1;
      *(float4*)&lv[r0][c0] = rv0; *(float4*)&lv[r0 + 16][c0] = rv1;
      __syncthreads();             // writes visible before next compute
    }
  }

  float* pd = Pm + ((size_t)ck * BH + bh) * MM;
  #pragma unroll
  for (int i = 0; i < 4; ++i)
    *(float4*)&pd[(d0 + i) * Dc + e0] =
        make_float4(acc[i][0], acc[i][1], acc[i][2], acc[i][3]);
  if (tid < Dc) Pz[((size_t)ck * BH + bh) * Dc + tid] = zacc;
}

// ---- Kernel 2: reduce M partials (f32); z = f64 exact sum ROUNDED TO F32 (the key step) ----
__global__ __launch_bounds__(256) void k2_reduce(const float* __restrict__ Pm,
                                                 const double* __restrict__ Pz,
                                                 float* __restrict__ Fm,
                                                 float* __restrict__ Fz) {
  const int i = blockIdx.x * 256 + threadIdx.x;
  const int nm = BH * MM;
  if (i < nm) {
    float s = 0.f;
    #pragma unroll
    for (int c = 0; c < SS; ++c) s += Pm[(size_t)c * nm + i];
    Fm[i] = s;
  }
  const int nz = BH * Dc;
  if (i < nz) {
    double s = 0.0;
    #pragma unroll
    for (int c = 0; c < SS; ++c) s += Pz[(size_t)c * nz + i];
    Fz[i] = (float)s;   // z rounded to f32: matches np's f32 intermediate bitwise
  }
}

// ---- Kernel 3: out = (q @ M) / (q . z_f32 + eps); den in f64 FROM THE F32 z ----
__global__ __launch_bounds__(256) void k3_retrieve(const float* __restrict__ Q,
                                                   const float* __restrict__ Fm,
                                                   const float* __restrict__ Fz,
                                                   float* __restrict__ O) {
  const int blk = blockIdx.x;             // BH * (Sc/QT) = 128*32
  const int bh = blk >> 5;
  const int row0 = (blk & 31) * QT;

  __shared__ __align__(16) float lm[Dc][Dc];     // 16 KB
  __shared__ __align__(16) float lq[QT][68];     // padded: row stride 68 floats
  __shared__ __align__(16) float lz[Dc];         // f32 z (the np intermediate)

  const int tid = threadIdx.x;

  // stage M: contiguous 16 KB
  const float4* gm4 = (const float4*)(Fm + (size_t)bh * MM);
  float4* lm4 = (float4*)&lm[0][0];
  #pragma unroll
  for (int j = 0; j < 4; ++j) lm4[tid + j * 256] = gm4[tid + j * 256];
  if (tid < Dc) lz[tid] = Fz[(size_t)bh * Dc + tid];

  // stage q rows (coalesced global, padded LDS rows)
  const float4* gq4 = (const float4*)(Q + ((size_t)bh * Sc + row0) * Dc);
  #pragma unroll
  for (int j = 0; j < 8; ++j) {
    const int i4 = tid + j * 256;
    const float4 v = gq4[i4];
    const int f = i4 * 4;
    *(float4*)&lq[f >> 6][f & 63] = v;
  }
  __syncthreads();

  const int rt = tid >> 2;       // 0..63 -> row pair
  const int et = tid & 3;        // 0..3  -> 16-col block
  const int r0 = rt * 2;
  const int e0 = et * 16;

  float acc0[16] = {}, acc1[16] = {};
  double den0 = 0.0, den1 = 0.0;

  #pragma unroll
  for (int ds = 0; ds < 16; ++ds) {
    const int d0 = ds * 4;
    const float4 q0 = *(const float4*)&lq[r0][d0];
    const float4 q1 = *(const float4*)&lq[r0 + 1][d0];
    const float4 z4 = *(const float4*)&lz[d0];
    const float* q0f = (const float*)&q0;
    const float* q1f = (const float*)&q1;
    const float* zf  = (const float*)&z4;
    #pragma unroll
    for (int i = 0; i < 4; ++i) {
      const double zd = (double)zf[i];
      den0 += (double)q0f[i] * zd;
      den1 += (double)q1f[i] * zd;
      #pragma unroll
      for (int j4 = 0; j4 < 4; ++j4) {
        const float4 m4 = *(const float4*)&lm[d0 + i][e0 + j4 * 4];
        const float* mf = (const float*)&m4;
        #pragma unroll
        for (int j = 0; j < 4; ++j) {
          acc0[j4 * 4 + j] = fmaf(q0f[i], mf[j], acc0[j4 * 4 + j]);
          acc1[j4 * 4 + j] = fmaf(q1f[i], mf[j], acc1[j4 * 4 + j]);
        }
      }
    }
  }

  const double i0 = 1.0 / (den0 + 1e-6);
  const double i1 = 1.0 / (den1 + 1e-6);

  float* go0 = O + ((size_t)bh * Sc + row0 + r0) * Dc + e0;
  float* go1 = go0 + Dc;
  #pragma unroll
  for (int j4 = 0; j4 < 4; ++j4) {
    ((float4*)go0)[j4] = make_float4((float)((double)acc0[j4 * 4 + 0] * i0),
                                     (float)((double)acc0[j4 * 4 + 1] * i0),
                                     (float)((double)acc0[j4 * 4 + 2] * i0),
                                     (float)((double)acc0[j4 * 4 + 3] * i0));
    ((float4*)go1)[j4] = make_float4((float)((double)acc1[j4 * 4 + 0] * i1),
                                     (float)((double)acc1[j4 * 4 + 1] * i1),
                                     (float)((double)acc1[j4 * 4 + 2] * i1),
                                     (float)((double)acc1[j4 * 4 + 3] * i1));
  }
}

extern "C" void kernel_launch(void* const* d_in, const int* in_sizes, int n_in,
                              void* d_out, int out_size, void* d_ws, size_t ws_size,
                              hipStream_t stream) {
  const float* K = (const float*)d_in[0];   // keys    [B,H,S,D]
  const float* V = (const float*)d_in[1];   // values
  const float* Q = (const float*)d_in[2];   // queries
  float* O = (float*)d_out;                 // [B,H,S,D]

  float* Pm = (float*)d_ws;                                  // SS*BH*MM floats  (16.8 MB)
  float* Fm = Pm + (size_t)SS * BH * MM;                     // BH*MM floats     (2.1 MB)
  double* Pz = (double*)(Fm + (size_t)BH * MM);              // SS*BH*Dc doubles (512 KB)
  float* Fz = (float*)(Pz + (size_t)SS * BH * Dc);           // BH*Dc floats     (32 KB)

  hipLaunchKernelGGL(k1_accum, dim3(BH * SS), dim3(256), 0, stream, K, V, Pm, Pz);
  hipLaunchKernelGGL(k2_reduce, dim3((BH * MM + 255) / 256), dim3(256), 0, stream, Pm, Pz, Fm, Fz);
  hipLaunchKernelGGL(k3_retrieve, dim3(BH * (Sc / QT)), dim3(256), 0, stream, Q, Fm, Fz, O);
}

// Round 5
// 182.129 us; speedup vs baseline: 1.2173x; 1.2173x over previous
//
#include <hip/hip_runtime.h>

constexpr int Bc = 8, Hc = 16, Sc = 4096, Dc = 64;
constexpr int BH = Bc * Hc;               // 128
constexpr int SS = 8;                     // s-split chunks in k1
constexpr int CHUNK = Sc / SS;            // 512 rows per block
constexpr int STG = 16;                   // rows staged per step
constexpr int NST = CHUNK / STG;          // 32 stages
constexpr int MM = Dc * Dc;               // 4096 floats of M per (bh)
constexpr int NZP = SS * 4;               // 32 z partials (per-wave)
constexpr int QT = 128;                   // q-rows per block in k3

// ---- Kernel 1: M partial via 8x8 reg tiles, wave-split rows; z f64 spread over waves ----
__global__ __launch_bounds__(256, 4) void k1_accum(const float* __restrict__ K,
                                                   const float* __restrict__ V,
                                                   float* __restrict__ Pm,
                                                   double* __restrict__ Pz) {
  const int blk = blockIdx.x;
  const int bh = blk >> 3;       // 0..127
  const int ck = blk & 7;        // 0..7
  const size_t base = ((size_t)bh * Sc + (size_t)ck * CHUNK) * Dc;
  const float4* gk4 = (const float4*)(K + base);
  const float4* gv4 = (const float4*)(V + base);

  // smem: lk[2][16][64] at [buf*1024]; lv[2][16][64] at [2048 + buf*1024]  (16 KB total)
  __shared__ __align__(16) float smem[4096];

  const int tid = threadIdx.x;
  const int w = tid >> 6;        // wave 0..3 (owns rows w*4..w*4+3 of each stage)
  const int l = tid & 63;
  const int d0 = (l >> 3) * 8;   // tile rows (k-dim)
  const int e0 = (l & 7) * 8;    // tile cols (v-dim)

  float acc[8][8] = {};          // per-wave partial of M[d0..+8][e0..+8]
  double zacc = 0.0;             // exact z partial (order-free)

  const int srow = tid >> 4;           // staging row 0..15
  const int scol = (tid & 15) * 4;     // staging col (floats)

  // prologue: stage 0
  float4 rk = gk4[tid], rv = gv4[tid];
  *(float4*)&smem[srow * 64 + scol] = rk;
  *(float4*)&smem[2048 + srow * 64 + scol] = rv;
  __syncthreads();

  for (int st = 0; st < NST; ++st) {
    const int cur = st & 1, nxt = cur ^ 1;
    if (st + 1 < NST) {               // issue next-stage loads early (hide under compute)
      rk = gk4[(st + 1) * 256 + tid];
      rv = gv4[(st + 1) * 256 + tid];
    }
    const float* lkc = &smem[cur * 1024];
    const float* lvc = &smem[2048 + cur * 1024];
    #pragma unroll
    for (int r = 0; r < 4; ++r) {
      const int row = w * 4 + r;
      const float4 ka = *(const float4*)&lkc[row * 64 + d0];
      const float4 kb = *(const float4*)&lkc[row * 64 + d0 + 4];
      const float4 va = *(const float4*)&lvc[row * 64 + e0];
      const float4 vb = *(const float4*)&lvc[row * 64 + e0 + 4];
      const float kk[8] = {ka.x, ka.y, ka.z, ka.w, kb.x, kb.y, kb.z, kb.w};
      const float vv[8] = {va.x, va.y, va.z, va.w, vb.x, vb.y, vb.z, vb.w};
      #pragma unroll
      for (int a = 0; a < 8; ++a)
        #pragma unroll
        for (int b = 0; b < 8; ++b)
          acc[a][b] = fmaf(kk[a], vv[b], acc[a][b]);
    }
    // z: wave w sums its 4 rows, lane l handles d = l (consecutive -> conflict-free)
    #pragma unroll
    for (int r = 0; r < 4; ++r)
      zacc += (double)lkc[(w * 4 + r) * 64 + l];
    // write next stage late (vmcnt wait overlapped with the compute above)
    if (st + 1 < NST) {
      *(float4*)&smem[nxt * 1024 + srow * 64 + scol] = rk;
      *(float4*)&smem[2048 + nxt * 1024 + srow * 64 + scol] = rv;
    }
    __syncthreads();   // single barrier per stage (dbuf: reads=cur, writes=nxt)
  }

  // combine 4 wave-partials of M in smem (serial over waves; amortized once/block)
  #pragma unroll
  for (int p = 0; p < 4; ++p) {
    if (w == p) {
      #pragma unroll
      for (int a = 0; a < 8; ++a) {
        float* dst = &smem[(d0 + a) * 64 + e0];
        float4 lo = make_float4(acc[a][0], acc[a][1], acc[a][2], acc[a][3]);
        float4 hi = make_float4(acc[a][4], acc[a][5], acc[a][6], acc[a][7]);
        if (p == 0) {
          *(float4*)dst = lo; *(float4*)(dst + 4) = hi;
        } else {
          float4 olo = *(float4*)dst, ohi = *(float4*)(dst + 4);
          olo.x += lo.x; olo.y += lo.y; olo.z += lo.z; olo.w += lo.w;
          ohi.x += hi.x; ohi.y += hi.y; ohi.z += hi.z; ohi.w += hi.w;
          *(float4*)dst = olo; *(float4*)(dst + 4) = ohi;
        }
      }
    }
    __syncthreads();
  }

  // coalesced Pm write from smem
  float* pd = Pm + ((size_t)ck * BH + bh) * MM;
  #pragma unroll
  for (int j = 0; j < 4; ++j) {
    const int idx = tid + j * 256;
    ((float4*)pd)[idx] = *(const float4*)&smem[idx * 4];
  }
  Pz[((size_t)(ck * 4 + w) * BH + bh) * Dc + l] = zacc;
}

// ---- Kernel 2: reduce M partials (f32); z = f64 exact sum ROUNDED TO F32 ----
__global__ __launch_bounds__(256) void k2_reduce(const float* __restrict__ Pm,
                                                 const double* __restrict__ Pz,
                                                 float* __restrict__ Fm,
                                                 float* __restrict__ Fz) {
  const int i = blockIdx.x * 256 + threadIdx.x;
  const int nm = BH * MM;
  if (i < nm) {
    float s = 0.f;
    #pragma unroll
    for (int c = 0; c < SS; ++c) s += Pm[(size_t)c * nm + i];
    Fm[i] = s;
  }
  const int nz = BH * Dc;
  if (i < nz) {
    double s = 0.0;
    #pragma unroll
    for (int c = 0; c < NZP; ++c) s += Pz[(size_t)c * nz + i];
    Fz[i] = (float)s;   // f32 intermediate matches np bitwise
  }
}

// ---- Kernel 3: out = (q @ M) / (q . z_f32 + eps); den in f64 FROM THE F32 z ----
__global__ __launch_bounds__(256) void k3_retrieve(const float* __restrict__ Q,
                                                   const float* __restrict__ Fm,
                                                   const float* __restrict__ Fz,
                                                   float* __restrict__ O) {
  const int blk = blockIdx.x;             // BH * (Sc/QT) = 128*32
  const int bh = blk >> 5;
  const int row0 = (blk & 31) * QT;

  __shared__ __align__(16) float lm[Dc][Dc];     // 16 KB
  __shared__ __align__(16) float lq[QT][68];     // padded: row stride 68 floats
  __shared__ __align__(16) float lz[Dc];         // f32 z (the np intermediate)

  const int tid = threadIdx.x;

  // stage M: contiguous 16 KB
  const float4* gm4 = (const float4*)(Fm + (size_t)bh * MM);
  float4* lm4 = (float4*)&lm[0][0];
  #pragma unroll
  for (int j = 0; j < 4; ++j) lm4[tid + j * 256] = gm4[tid + j * 256];
  if (tid < Dc) lz[tid] = Fz[(size_t)bh * Dc + tid];

  // stage q rows (coalesced global, padded LDS rows)
  const float4* gq4 = (const float4*)(Q + ((size_t)bh * Sc + row0) * Dc);
  #pragma unroll
  for (int j = 0; j < 8; ++j) {
    const int i4 = tid + j * 256;
    const float4 v = gq4[i4];
    const int f = i4 * 4;
    *(float4*)&lq[f >> 6][f & 63] = v;
  }
  __syncthreads();

  const int rt = tid >> 2;       // 0..63 -> row pair
  const int et = tid & 3;        // 0..3  -> 16-col block
  const int r0 = rt * 2;
  const int e0 = et * 16;

  float acc0[16] = {}, acc1[16] = {};
  double den0 = 0.0, den1 = 0.0;

  #pragma unroll
  for (int ds = 0; ds < 16; ++ds) {
    const int d0 = ds * 4;
    const float4 q0 = *(const float4*)&lq[r0][d0];
    const float4 q1 = *(const float4*)&lq[r0 + 1][d0];
    const float4 z4 = *(const float4*)&lz[d0];
    const float* q0f = (const float*)&q0;
    const float* q1f = (const float*)&q1;
    const float* zf  = (const float*)&z4;
    #pragma unroll
    for (int i = 0; i < 4; ++i) {
      const double zd = (double)zf[i];
      den0 += (double)q0f[i] * zd;
      den1 += (double)q1f[i] * zd;
      #pragma unroll
      for (int j4 = 0; j4 < 4; ++j4) {
        const float4 m4 = *(const float4*)&lm[d0 + i][e0 + j4 * 4];
        const float* mf = (const float*)&m4;
        #pragma unroll
        for (int j = 0; j < 4; ++j) {
          acc0[j4 * 4 + j] = fmaf(q0f[i], mf[j], acc0[j4 * 4 + j]);
          acc1[j4 * 4 + j] = fmaf(q1f[i], mf[j], acc1[j4 * 4 + j]);
        }
      }
    }
  }

  const double i0 = 1.0 / (den0 + 1e-6);
  const double i1 = 1.0 / (den1 + 1e-6);

  float* go0 = O + ((size_t)bh * Sc + row0 + r0) * Dc + e0;
  float* go1 = go0 + Dc;
  #pragma unroll
  for (int j4 = 0; j4 < 4; ++j4) {
    ((float4*)go0)[j4] = make_float4((float)((double)acc0[j4 * 4 + 0] * i0),
                                     (float)((double)acc0[j4 * 4 + 1] * i0),
                                     (float)((double)acc0[j4 * 4 + 2] * i0),
                                     (float)((double)acc0[j4 * 4 + 3] * i0));
    ((float4*)go1)[j4] = make_float4((float)((double)acc1[j4 * 4 + 0] * i1),
                                     (float)((double)acc1[j4 * 4 + 1] * i1),
                                     (float)((double)acc1[j4 * 4 + 2] * i1),
                                     (float)((double)acc1[j4 * 4 + 3] * i1));
  }
}

extern "C" void kernel_launch(void* const* d_in, const int* in_sizes, int n_in,
                              void* d_out, int out_size, void* d_ws, size_t ws_size,
                              hipStream_t stream) {
  const float* K = (const float*)d_in[0];   // keys    [B,H,S,D]
  const float* V = (const float*)d_in[1];   // values
  const float* Q = (const float*)d_in[2];   // queries
  float* O = (float*)d_out;                 // [B,H,S,D]

  float* Pm = (float*)d_ws;                                  // SS*BH*MM floats  (16.8 MB)
  float* Fm = Pm + (size_t)SS * BH * MM;                     // BH*MM floats     (2.1 MB)
  double* Pz = (double*)(Fm + (size_t)BH * MM);              // NZP*BH*Dc doubles (2.1 MB)
  float* Fz = (float*)(Pz + (size_t)NZP * BH * Dc);          // BH*Dc floats     (32 KB)

  hipLaunchKernelGGL(k1_accum, dim3(BH * SS), dim3(256), 0, stream, K, V, Pm, Pz);
  hipLaunchKernelGGL(k2_reduce, dim3((BH * MM + 255) / 256), dim3(256), 0, stream, Pm, Pz, Fm, Fz);
  hipLaunchKernelGGL(k3_retrieve, dim3(BH * (Sc / QT)), dim3(256), 0, stream, Q, Fm, Fz, O);
}